// Round 18
// baseline (154.545 us; speedup 1.0000x reference)
//
#include <hip/hip_runtime.h>
#include <hip/hip_bf16.h>

#define DI __device__ __forceinline__

namespace {
constexpr int N_ = 128, S_ = 32, P_ = 16, F_ = 256, H_ = 4, NH_ = 128;
constexpr int SP_ = S_ * P_;          // 512
constexpr int GC_ = H_ * NH_;         // 512
constexpr float SLOPE_ = 0.2f;
constexpr int OUT_ELEMS = N_ * SP_ * NH_;    // 8,388,608
}

DI float lrelu(float x) { return fmaxf(x, SLOPE_ * x); }   // exact for slope<1

DI unsigned short f2h(float x) {
    _Float16 h = (_Float16)x;
    return __builtin_bit_cast(unsigned short, h);
}
DI float h2f(unsigned short b) {
    return (float)__builtin_bit_cast(_Float16, b);
}

typedef __fp16   fp16x2 __attribute__((ext_vector_type(2)));
typedef _Float16 f16x8 __attribute__((ext_vector_type(8)));
typedef float    f32x4 __attribute__((ext_vector_type(4)));

DI unsigned int pk2(float a, float b) {          // packed f16 convert (RTZ)
    fp16x2 r = __builtin_amdgcn_cvt_pkrtz(a, b);
    return __builtin_bit_cast(unsigned int, r);
}

DI f32x4 mfma16h(uint4 a, uint4 b, f32x4 c) {
    return __builtin_amdgcn_mfma_f32_16x16x32_f16(
        __builtin_bit_cast(f16x8, a), __builtin_bit_cast(f16x8, b), c, 0, 0, 0);
}

// ---------------------------------------------------------------------------
// prep_all: all 64 blocks split Wr*256 into f16 hi/lo transposed bt[col][k];
// blocks 0-7 additionally compute wls/wrs (attn-weight-collapsed projections).
__global__ __launch_bounds__(256) void prep_all(
    const float* __restrict__ Wl, const float* __restrict__ Wr,
    const float* __restrict__ aw, float* __restrict__ wls, float* __restrict__ wrs,
    unsigned short* __restrict__ bth, unsigned short* __restrict__ btl) {
    int t = blockIdx.x * 256 + threadIdx.x;   // 0..16383
    {   // prep_bt part
        int col = t >> 5, k0 = (t & 31) * 8;
        union { unsigned short us[8]; uint4 v; } ph, pl;
#pragma unroll
        for (int e = 0; e < 8; ++e) {
            float v = Wr[(size_t)(k0 + e) * GC_ + col] * 256.0f;
            unsigned short hi = f2h(v);
            ph.us[e] = hi;
            pl.us[e] = f2h(v - h2f(hi));
        }
        *(uint4*)&bth[col * F_ + k0] = ph.v;
        *(uint4*)&btl[col * F_ + k0] = pl.v;
    }
    if (t < 2048) {   // prep part
        int which = t >> 10;
        int f = (t & 1023) >> 2;
        int h = t & 3;
        const float* W = which ? Wr : Wl;
        const float* a = aw + which * NH_;
        const float* wrow = W + (size_t)f * GC_ + h * NH_;
        float s = 0.f;
        for (int k = 0; k < NH_; ++k) s += wrow[k] * a[k];
        (which ? wrs : wls)[f * H_ + h] = s;
    }
}

// ---------------------------------------------------------------------------
// Fully fused per-sp kernel (r13 schedule + in-loop score computation):
//   wl/wr LDS staging -> K-loop {next-A loads, B frags, MFMA, convert+write
//   next A + score-partial FMAs, barrier} -> gt epilogue + score shfl-reduce
//   -> max-scan -> pass1 -> barrier-free PV per head {pa-gen, setprio MFMA,
//   a_out 32-row chunk} -> out epilogue.
__global__ __launch_bounds__(512, 2) void gat_fused(
    const float* __restrict__ hm,
    const unsigned short* __restrict__ bth, const unsigned short* __restrict__ btl,
    const float* __restrict__ wls, const float* __restrict__ wrs,
    float* __restrict__ a_out, float* __restrict__ out) {
    constexpr int PA = 40;
    __shared__ __align__(16) unsigned char SMEM[149632];
    unsigned short* Ah0 = (unsigned short*)SMEM;               // [128*PA]
    unsigned short* Ah1 = Ah0 + 128 * PA;
    unsigned short* Al0 = Ah1 + 128 * PA;
    unsigned short* Al1 = Al0 + 128 * PA;                      // 40960 B total
    unsigned short* gt4 = (unsigned short*)SMEM;               // [4][128][128] after GEMM
    float4* sl4   = (float4*)(SMEM + 131072);                  // 2048 B
    float4* sr4   = (float4*)(SMEM + 133120);                  // 2048 B
    float4* mrow4 = (float4*)(SMEM + 135168);                  // 2048 B
    float4* invs4 = (float4*)(SMEM + 137216);                  // 2048 B
    float*  slh   = (float*)(SMEM + 139264);                   // [4][132] = 2112 B
    float*  mx1   = (float*)(SMEM + 141392);
    float*  mx2   = (float*)(SMEM + 141408);
    int*    id1   = (int*)(SMEM + 141424);
    float*  wlp   = (float*)(SMEM + 141440);                   // float4[256] = 4096 B
    float*  wrp   = (float*)(SMEM + 145536);                   // float4[256] = 4096 B
    // scratch for max-scan (inside mrow4 region, dead until pass1):
    float* pm1 = (float*)mrow4;          // [4][32]
    float* pm2 = pm1 + 128;              // [4][32]
    int*   pid = (int*)(pm2 + 128);      // [4][32]

    int sp = blockIdx.x;
    int t = threadIdx.x;
    int w = t >> 6, l = t & 63;
    int ls = l & 15, kg = l >> 4;

    // ---- stage wls/wrs into LDS (float4 per k) ----
    if (t < 256)       *(float4*)&wlp[t * 4]         = ((const float4*)wls)[t];
    else if (t < 512)  *(float4*)&wrp[(t - 256) * 4] = ((const float4*)wrs)[t - 256];

    // ---- issue step-0 A loads early ----
    int arow = t >> 2, akc = (t & 3) * 8;
    const float* abase = hm + ((size_t)arow * 512 + sp) * 256 + akc;
    float4 s0 = *(const float4*)(abase);
    float4 s1 = *(const float4*)(abase + 4);
    __syncthreads();

    float scl[4] = {0.f, 0.f, 0.f, 0.f};
    float scr[4] = {0.f, 0.f, 0.f, 0.f};

    // ---- convert + write A step-0, with score partials ----
    {
        float av[8] = {s0.x, s0.y, s0.z, s0.w, s1.x, s1.y, s1.z, s1.w};
        uint4 vh, vl;
        unsigned int* ph = (unsigned int*)&vh;
        unsigned int* pl = (unsigned int*)&vl;
#pragma unroll
        for (int e = 0; e < 8; e += 2) {
            unsigned int hp = pk2(av[e], av[e + 1]);
            float r0 = av[e]     - h2f((unsigned short)(hp & 0xffff));
            float r1 = av[e + 1] - h2f((unsigned short)(hp >> 16));
            ph[e >> 1] = hp;
            pl[e >> 1] = pk2(r0, r1);
        }
        *(uint4*)&Ah0[arow * PA + akc] = vh;
        *(uint4*)&Al0[arow * PA + akc] = vl;
#pragma unroll
        for (int e = 0; e < 8; ++e) {
            int k = akc + e;
            float4 wl = *(const float4*)&wlp[k * 4];
            float4 wr = *(const float4*)&wrp[k * 4];
            scl[0] += av[e] * wl.x; scl[1] += av[e] * wl.y;
            scl[2] += av[e] * wl.z; scl[3] += av[e] * wl.w;
            scr[0] += av[e] * wr.x; scr[1] += av[e] * wr.y;
            scr[2] += av[e] * wr.z; scr[3] += av[e] * wr.w;
        }
    }
    __syncthreads();

    f32x4 acc[8][4];
#pragma unroll
    for (int m = 0; m < 8; ++m)
#pragma unroll
        for (int n = 0; n < 4; ++n) acc[m][n] = (f32x4){0.f, 0.f, 0.f, 0.f};

    // ---- K-loop: GEMM + in-staging score partials ----
    for (int step = 0; step < 8; ++step) {
        unsigned short* AhC = (step & 1) ? Ah1 : Ah0;
        unsigned short* AlC = (step & 1) ? Al1 : Al0;
        unsigned short* AhN = (step & 1) ? Ah0 : Ah1;
        unsigned short* AlN = (step & 1) ? Al0 : Al1;
        // (1) issue next-A f32 loads
        float4 n0, n1;
        if (step < 7) {
            n0 = *(const float4*)(abase + (step + 1) * 32);
            n1 = *(const float4*)(abase + (step + 1) * 32 + 4);
        }
        // (2) issue B fragment loads (L2)
        int kglob = step * 32 + kg * 8;
        uint4 fbh[4], fbl[4];
#pragma unroll
        for (int n = 0; n < 4; ++n) {
            int c = n * 128 + w * 16 + ls;
            fbh[n] = *(const uint4*)&bth[(size_t)c * F_ + kglob];
            fbl[n] = *(const uint4*)&btl[(size_t)c * F_ + kglob];
        }
        // (3) MFMA
#pragma unroll
        for (int m = 0; m < 8; ++m) {
            int row = m * 16 + ls;
            uint4 fah = *(const uint4*)&AhC[row * PA + kg * 8];
            uint4 fal = *(const uint4*)&AlC[row * PA + kg * 8];
#pragma unroll
            for (int n = 0; n < 4; ++n) {
                acc[m][n] = mfma16h(fah, fbh[n], acc[m][n]);
                acc[m][n] = mfma16h(fah, fbl[n], acc[m][n]);
                acc[m][n] = mfma16h(fal, fbh[n], acc[m][n]);
            }
        }
        // (4) convert + write next A, plus score partial FMAs
        if (step < 7) {
            float av[8] = {n0.x, n0.y, n0.z, n0.w, n1.x, n1.y, n1.z, n1.w};
            uint4 vh, vl;
            unsigned int* ph = (unsigned int*)&vh;
            unsigned int* pl = (unsigned int*)&vl;
#pragma unroll
            for (int e = 0; e < 8; e += 2) {
                unsigned int hp = pk2(av[e], av[e + 1]);
                float r0 = av[e]     - h2f((unsigned short)(hp & 0xffff));
                float r1 = av[e + 1] - h2f((unsigned short)(hp >> 16));
                ph[e >> 1] = hp;
                pl[e >> 1] = pk2(r0, r1);
            }
            *(uint4*)&AhN[arow * PA + akc] = vh;
            *(uint4*)&AlN[arow * PA + akc] = vl;
            int kb = (step + 1) * 32 + akc;
#pragma unroll
            for (int e = 0; e < 8; ++e) {
                int k = kb + e;
                float4 wl = *(const float4*)&wlp[k * 4];
                float4 wr = *(const float4*)&wrp[k * 4];
                scl[0] += av[e] * wl.x; scl[1] += av[e] * wl.y;
                scl[2] += av[e] * wl.z; scl[3] += av[e] * wl.w;
                scr[0] += av[e] * wr.x; scr[1] += av[e] * wr.y;
                scr[2] += av[e] * wr.z; scr[3] += av[e] * wr.w;
            }
        }
        __syncthreads();
    }

    // ---- GEMM epilogue: all-heads gt (A buffers dead; union reuse) ----
    int fl  = w * 16 + ls;
    int swz = (ls & 7) << 3;
    constexpr float gs = 0.00390625f;
#pragma unroll
    for (int m = 0; m < 8; ++m) {
        int nx = (m * 16 + kg * 4) ^ swz;
#pragma unroll
        for (int h = 0; h < H_; ++h) {
            uint2 pk;
            pk.x = pk2(acc[m][h][0] * gs, acc[m][h][1] * gs);
            pk.y = pk2(acc[m][h][2] * gs, acc[m][h][3] * gs);
            *(uint2*)&gt4[h * 16384 + fl * 128 + nx] = pk;
        }
    }

    // ---- score reduce: 4 threads per row -> full dot; write sl4/slh/sr4 ----
#pragma unroll
    for (int h = 0; h < H_; ++h) {
        scl[h] += __shfl_xor(scl[h], 1);
        scl[h] += __shfl_xor(scl[h], 2);
        scr[h] += __shfl_xor(scr[h], 1);
        scr[h] += __shfl_xor(scr[h], 2);
    }
    if ((t & 3) == 0) {
        int row = t >> 2;
        sl4[row] = (float4){scl[0], scl[1], scl[2], scl[3]};
        sr4[row] = (float4){scr[0], scr[1], scr[2], scr[3]};
        slh[0 * 132 + row] = scl[0]; slh[1 * 132 + row] = scl[1];
        slh[2 * 132 + row] = scl[2]; slh[3 * 132 + row] = scl[3];
    }
    __syncthreads();

    // ---- parallel max1/max2(+argmax) of sl per head ----
    if (t < 128) {
        int h = t >> 5, seg = t & 31;
        float m1 = -1e30f, m2 = -1e30f; int i1 = -1;
#pragma unroll
        for (int jj = 0; jj < 4; ++jj) {
            int j = seg * 4 + jj;
            float v = slh[h * 132 + j];
            if (v > m1) { m2 = m1; m1 = v; i1 = j; }
            else m2 = fmaxf(m2, v);
        }
        pm1[h * 32 + seg] = m1; pm2[h * 32 + seg] = m2; pid[h * 32 + seg] = i1;
    }
    __syncthreads();
    if (t < H_) {
        float m1 = -1e30f, m2 = -1e30f; int i1 = -1;
        for (int s = 0; s < 32; ++s) {
            float a1 = pm1[t * 32 + s], a2 = pm2[t * 32 + s]; int ai = pid[t * 32 + s];
            if (a1 > m1) { m2 = fmaxf(m1, a2); m1 = a1; i1 = ai; }
            else m2 = fmaxf(m2, a1);
        }
        mx1[t] = m1; mx2[t] = m2; id1[t] = i1;
    }
    __syncthreads();

    // ---- pass1: per-(i,h) row max and inv-sum (writes mrow4/invs4) ----
    {
        int i = t & 127, h = t >> 7;
        float sri = ((const float*)&sr4[i])[h];
        float m = lrelu(sri + ((id1[h] == i) ? mx2[h] : mx1[h]));
        float sum = 0.f;
        for (int j = 0; j < N_; ++j) {
            float e = lrelu(sri + slh[h * 132 + j]);
            float p = __expf(e - m);
            if (j != i) sum += p;
        }
        ((float*)&mrow4[i])[h] = m;
        ((float*)&invs4[i])[h] = 1.f / sum;
    }
    __syncthreads();

    // ---- PV phase (barrier-free): per head {pa-gen, MFMA, a_out chunk} ----
    f32x4 aco[8];
#pragma unroll
    for (int n = 0; n < 8; ++n) aco[n] = (f32x4){0.f, 0.f, 0.f, 0.f};

    int i_my = w * 16 + ls;
    float4* a_base_g = (float4*)(a_out + (size_t)sp * 65536);
    int aj = t & 127, ib = t >> 7;
    float4 slv = sl4[aj];

    for (int h = 0; h < H_; ++h) {
        // pa-gen for head h
        float sri = ((const float*)&sr4[i_my])[h];
        float mh  = ((const float*)&mrow4[i_my])[h];
        float sh  = ((const float*)&invs4[i_my])[h];
        uint4 pa[4];
#pragma unroll
        for (int k0i = 0; k0i < 4; ++k0i) {
            int jb = k0i * 32 + kg * 8;
            union { unsigned short us[8]; uint4 v; } pk;
#pragma unroll
            for (int e = 0; e < 8; ++e) {
                int j = jb + e;
                float p = (j == i_my) ? 0.f
                        : __expf(lrelu(sri + slh[h * 132 + j]) - mh) * sh;
                pk.us[e] = f2h(p);
            }
            pa[k0i] = pk.v;
        }
        __builtin_amdgcn_s_setprio(1);
#pragma unroll
        for (int k0i = 0; k0i < 4; ++k0i) {
            int koff = k0i * 32 + kg * 8;
#pragma unroll
            for (int n = 0; n < 8; ++n) {
                int f = n * 16 + ls;
                uint4 fb = *(const uint4*)&gt4[h * 16384 + f * 128 + (koff ^ swz)];
                aco[n] = mfma16h(pa[k0i], fb, aco[n]);
            }
        }
        __builtin_amdgcn_s_setprio(0);
        // a_out chunk: rows h*32 .. h*32+31 (stores drain under next head)
#pragma unroll
        for (int q = 0; q < 8; ++q) {
            int i = h * 32 + q * 4 + ib;
            float4 srv = sr4[i], m4 = mrow4[i], s4 = invs4[i];
            float4 p;
            p.x = __expf(lrelu(srv.x + slv.x) - m4.x) * s4.x;
            p.y = __expf(lrelu(srv.y + slv.y) - m4.y) * s4.y;
            p.z = __expf(lrelu(srv.z + slv.z) - m4.z) * s4.z;
            p.w = __expf(lrelu(srv.w + slv.w) - m4.w) * s4.w;
            if (aj == i) { p.x = 0.f; p.y = 0.f; p.z = 0.f; p.w = 0.f; }
            a_base_g[i * N_ + aj] = p;
        }
    }

    // ---- out epilogue ----
#pragma unroll
    for (int n = 0; n < 8; ++n) {
        int f = n * 16 + ls;
#pragma unroll
        for (int q = 0; q < 4; ++q)
            out[(size_t)(w * 16 + kg * 4 + q) * 65536 + (size_t)sp * NH_ + f] =
                aco[n][q] * 0.25f;
    }
}

// ---------------------------------------------------------------------------
extern "C" void kernel_launch(void* const* d_in, const int* in_sizes, int n_in,
                              void* d_out, int out_size, void* d_ws, size_t ws_size,
                              hipStream_t stream) {
    const float* hm = (const float*)d_in[0];
    const float* Wl = (const float*)d_in[1];
    const float* Wr = (const float*)d_in[2];
    const float* aw = (const float*)d_in[3];

    float* out   = (float*)d_out;
    float* a_out = out + OUT_ELEMS;

    char* ws = (char*)d_ws;
    float* wls = (float*)ws;                                  // 4 KiB
    float* wrs = wls + F_ * H_;                               // 4 KiB
    unsigned short* bth = (unsigned short*)(wrs + F_ * H_);   // 256 KiB
    unsigned short* btl = bth + GC_ * F_;                     // 256 KiB

    prep_all  <<<64,  256, 0, stream>>>(Wl, Wr, aw, wls, wrs, bth, btl);
    gat_fused <<<SP_, 512, 0, stream>>>(hm, bth, btl, wls, wrs, a_out, out);
}